// Round 1
// baseline (1222.508 us; speedup 1.0000x reference)
//
#include <hip/hip_runtime.h>
#include <math.h>

// Problem constants (fixed by setup_inputs)
#define BB 8
#define NN 2048
#define HH 128
#define SEGCAP 24          // neighbor capacity per j-segment (mean ~2.2, Poisson tail ~1e-16)
#define MAXNBR (4*SEGCAP)  // 96 per node
#define PREDL 10
#define TSTRIDE (NN*3)
#define OUT_BSTRIDE ((PREDL+1)*NN*3)

// ---------------------------------------------------------------------------
// K0: states0 = [points, 0]; write t=0 output slice
// ---------------------------------------------------------------------------
__global__ __launch_bounds__(256) void k_init(const float* __restrict__ points,
                                              float* __restrict__ states,
                                              float* __restrict__ out) {
    int idx = blockIdx.x * 256 + threadIdx.x;
    if (idx >= BB * NN) return;
    int b = idx >> 11;
    int n = idx & 2047;
    float px = points[idx * 3 + 0];
    float py = points[idx * 3 + 1];
    float pz = points[idx * 3 + 2];
    float* s = states + (size_t)idx * 6;
    s[0] = px; s[1] = py; s[2] = pz; s[3] = 0.f; s[4] = 0.f; s[5] = 0.f;
    float* o = out + (size_t)b * OUT_BSTRIDE + n * 3;
    o[0] = px; o[1] = py; o[2] = pz;
}

// ---------------------------------------------------------------------------
// K1: radius-graph (d2 < R^2, j != i), degree, dinv = 1/sqrt(deg+1),
//     xs0 = dinv * states (pre-scaled 6-ch rows for layer-0 aggregation).
// d2 computed in numpy's exact rounding order (no fma contraction) so that
// step-1 adjacency is bit-identical to the np reference.
// grid: 256 blocks (b = blk&7 for XCD locality, 64 nodes/block), 256 thr
// (4 threads per node, each scans a 512-wide j segment).
// ---------------------------------------------------------------------------
__global__ __launch_bounds__(256) void k_adj(const float* __restrict__ states,
                                             float* __restrict__ xs0,
                                             float* __restrict__ dinv,
                                             int* __restrict__ nbr,
                                             int* __restrict__ cnt4) {
    const float R2c = 0.01f;
    int b = blockIdx.x & 7;
    int tile = blockIdx.x >> 3;
    __shared__ float4 pos[NN];     // 32 KiB
    __shared__ int degs[256];
    const float* sb = states + (size_t)b * NN * 6;
    for (int j = threadIdx.x; j < NN; j += 256) {
        const float* r = sb + j * 6;
        pos[j] = make_float4(r[0], r[1], r[2], 0.f);
    }
    __syncthreads();
    int local = threadIdx.x >> 2;
    int seg = threadIdx.x & 3;
    int i = tile * 64 + local;
    int gi = b * NN + i;
    float4 pi = pos[i];
    int cnt = 0;
    int base = gi * MAXNBR + seg * SEGCAP;
    int j0 = seg * 512;
    for (int j = j0; j < j0 + 512; ++j) {
        float4 pj = pos[j];
        float dx = pi.x - pj.x;
        float dy = pi.y - pj.y;
        float dz = pi.z - pj.z;
        // exact np order: (dx*dx + dy*dy) + dz*dz, each op rounded, no fma
        float d2 = __fadd_rn(__fadd_rn(__fmul_rn(dx, dx), __fmul_rn(dy, dy)),
                             __fmul_rn(dz, dz));
        if (d2 < R2c && j != i) {
            if (cnt < SEGCAP) nbr[base + cnt] = j;
            cnt++;
        }
    }
    if (cnt > SEGCAP) cnt = SEGCAP;
    cnt4[gi * 4 + seg] = cnt;
    degs[threadIdx.x] = cnt;
    __syncthreads();
    if (seg == 0) {
        int rs = 1 + degs[threadIdx.x] + degs[threadIdx.x + 1]
                   + degs[threadIdx.x + 2] + degs[threadIdx.x + 3];
        float di = (float)(1.0 / sqrt((double)rs));  // correctly-rounded rsqrt
        dinv[gi] = di;
        const float* srow = sb + i * 6;
        float* xr = xs0 + (size_t)gi * 6;
#pragma unroll
        for (int c = 0; c < 6; ++c) xr[c] = di * srow[c];
    }
}

// ---------------------------------------------------------------------------
// K2: layer 0 (6 -> 128): u_i = dinv_i*(sum_nbr xs0_j + xs0_i);
//     xs1 = dinv_i * relu(u @ W0 + b0)
// grid: 256 blocks (64 nodes each), 256 thr (4 thr/node x 32 ch)
// ---------------------------------------------------------------------------
__global__ __launch_bounds__(256) void k_l0(const float* __restrict__ xs0,
                                            const float* __restrict__ dinv,
                                            const int* __restrict__ nbr,
                                            const int* __restrict__ cnt4,
                                            const float* __restrict__ W0,
                                            const float* __restrict__ b0,
                                            float* __restrict__ xs1) {
    int b = blockIdx.x & 7;
    int tile = blockIdx.x >> 3;
    int node = threadIdx.x >> 2;
    int part = threadIdx.x & 3;
    int i = tile * 64 + node;
    int gi = b * NN + i;
    float g[6];
    {
        const float* sr = xs0 + (size_t)gi * 6;
#pragma unroll
        for (int c = 0; c < 6; ++c) g[c] = sr[c];
    }
    const int* nb = nbr + gi * MAXNBR;
    const int* c4 = cnt4 + gi * 4;
#pragma unroll
    for (int s = 0; s < 4; ++s) {
        int c = c4[s];
        for (int k = 0; k < c; ++k) {
            int j = nb[s * SEGCAP + k];
            const float* xr = xs0 + (size_t)(b * NN + j) * 6;
#pragma unroll
            for (int q = 0; q < 6; ++q) g[q] += xr[q];
        }
    }
    float di = dinv[gi];
#pragma unroll
    for (int c = 0; c < 6; ++c) g[c] *= di;
    int c0 = part * 32;
    float y[32];
#pragma unroll
    for (int r = 0; r < 8; ++r) {
        float4 bv = *(const float4*)(b0 + c0 + r * 4);
        y[r * 4 + 0] = bv.x; y[r * 4 + 1] = bv.y; y[r * 4 + 2] = bv.z; y[r * 4 + 3] = bv.w;
    }
#pragma unroll
    for (int k = 0; k < 6; ++k) {
        float u = g[k];
        const float* wr = W0 + k * HH + c0;
#pragma unroll
        for (int r = 0; r < 8; ++r) {
            float4 w = *(const float4*)(wr + r * 4);
            y[r * 4 + 0] = fmaf(u, w.x, y[r * 4 + 0]);
            y[r * 4 + 1] = fmaf(u, w.y, y[r * 4 + 1]);
            y[r * 4 + 2] = fmaf(u, w.z, y[r * 4 + 2]);
            y[r * 4 + 3] = fmaf(u, w.w, y[r * 4 + 3]);
        }
    }
    float* xo = xs1 + (size_t)gi * HH + c0;
#pragma unroll
    for (int r = 0; r < 8; ++r) {
        float4 v;
        v.x = di * fmaxf(y[r * 4 + 0], 0.f);
        v.y = di * fmaxf(y[r * 4 + 1], 0.f);
        v.z = di * fmaxf(y[r * 4 + 2], 0.f);
        v.w = di * fmaxf(y[r * 4 + 3], 0.f);
        *(float4*)(xo + r * 4) = v;
    }
}

// ---------------------------------------------------------------------------
// Shared pieces for the 128->128 layers.
// Tile = 32 nodes/block, 512 blocks (2/CU for latency hiding).
// Phase A: gather pre-scaled neighbor rows -> u tile in LDS (stride 132:
//          bank (4n+k)%32 -> <=2-way conflicts, free per m136).
// Phase B: y[32x128] = u @ W register-tiled GEMM (2 nodes x 8 ch / thread).
// ---------------------------------------------------------------------------
__device__ __forceinline__ void gather_into_lds(const float* __restrict__ xin,
                                                const float* __restrict__ dinv,
                                                const int* __restrict__ nbr,
                                                const int* __restrict__ cnt4,
                                                int b, int tile,
                                                float (*uS)[HH + 4]) {
    const int node = threadIdx.x >> 3;   // 0..31
    const int part = threadIdx.x & 7;    // 16 ch each
    const int i = tile * 32 + node;
    const int gi = b * NN + i;
    const int c0 = part * 16;
    float acc[16];
    const float* xs = xin + (size_t)gi * HH + c0;
#pragma unroll
    for (int r = 0; r < 4; ++r) *(float4*)&acc[r * 4] = *(const float4*)(xs + r * 4);
    const int* nb = nbr + gi * MAXNBR;
    const int* c4 = cnt4 + gi * 4;
#pragma unroll
    for (int s = 0; s < 4; ++s) {
        const int c = c4[s];
        for (int k = 0; k < c; ++k) {
            const int j = nb[s * SEGCAP + k];
            const float* xr = xin + (size_t)(b * NN + j) * HH + c0;
#pragma unroll
            for (int r = 0; r < 4; ++r) {
                float v[4];
                *(float4*)v = *(const float4*)(xr + r * 4);
                acc[r * 4 + 0] += v[0]; acc[r * 4 + 1] += v[1];
                acc[r * 4 + 2] += v[2]; acc[r * 4 + 3] += v[3];
            }
        }
    }
    const float di = dinv[gi];
#pragma unroll
    for (int r = 0; r < 4; ++r) {
        float4 o;
        o.x = acc[r * 4 + 0] * di; o.y = acc[r * 4 + 1] * di;
        o.z = acc[r * 4 + 2] * di; o.w = acc[r * 4 + 3] * di;
        *(float4*)&uS[node][c0 + r * 4] = o;
    }
}

__device__ __forceinline__ void gemm_tile(const float (*uS)[HH + 4],
                                          const float* __restrict__ W,
                                          const float* __restrict__ bias,
                                          float y0[8], float y1[8],
                                          int n0, int cc0) {
    float4 bv0 = *(const float4*)(bias + cc0);
    float4 bv1 = *(const float4*)(bias + cc0 + 4);
    y0[0] = bv0.x; y0[1] = bv0.y; y0[2] = bv0.z; y0[3] = bv0.w;
    y0[4] = bv1.x; y0[5] = bv1.y; y0[6] = bv1.z; y0[7] = bv1.w;
#pragma unroll
    for (int r = 0; r < 8; ++r) y1[r] = y0[r];
#pragma unroll 2
    for (int k = 0; k < HH; k += 4) {
        float ua[4], ub[4];
        *(float4*)ua = *(const float4*)&uS[n0][k];
        *(float4*)ub = *(const float4*)&uS[n0 + 1][k];
        const float* wrow = W + k * HH + cc0;
#pragma unroll
        for (int q = 0; q < 4; ++q) {
            float4 wa = *(const float4*)(wrow + q * HH);
            float4 wb = *(const float4*)(wrow + q * HH + 4);
            float u0 = ua[q], u1 = ub[q];
            y0[0] = fmaf(u0, wa.x, y0[0]); y0[1] = fmaf(u0, wa.y, y0[1]);
            y0[2] = fmaf(u0, wa.z, y0[2]); y0[3] = fmaf(u0, wa.w, y0[3]);
            y0[4] = fmaf(u0, wb.x, y0[4]); y0[5] = fmaf(u0, wb.y, y0[5]);
            y0[6] = fmaf(u0, wb.z, y0[6]); y0[7] = fmaf(u0, wb.w, y0[7]);
            y1[0] = fmaf(u1, wa.x, y1[0]); y1[1] = fmaf(u1, wa.y, y1[1]);
            y1[2] = fmaf(u1, wa.z, y1[2]); y1[3] = fmaf(u1, wa.w, y1[3]);
            y1[4] = fmaf(u1, wb.x, y1[4]); y1[5] = fmaf(u1, wb.y, y1[5]);
            y1[6] = fmaf(u1, wb.z, y1[6]); y1[7] = fmaf(u1, wb.w, y1[7]);
        }
    }
}

// K3: middle layer (layer 1): xs_out = dinv * relu(u @ W + b)
__global__ __launch_bounds__(256, 2) void k_mid(const float* __restrict__ xin,
                                                const float* __restrict__ dinv,
                                                const int* __restrict__ nbr,
                                                const int* __restrict__ cnt4,
                                                const float* __restrict__ W,
                                                const float* __restrict__ bias,
                                                float* __restrict__ xout) {
    __shared__ float uS[32][HH + 4];
    int b = blockIdx.x & 7;
    int tile = blockIdx.x >> 3;
    gather_into_lds(xin, dinv, nbr, cnt4, b, tile, uS);
    __syncthreads();
    int cb = threadIdx.x & 15;
    int n0 = (threadIdx.x >> 4) * 2;
    int cc0 = cb * 8;
    float y0[8], y1[8];
    gemm_tile(uS, W, bias, y0, y1, n0, cc0);
    int g0 = b * NN + tile * 32 + n0;
    float di0 = dinv[g0], di1 = dinv[g0 + 1];
    float* o0 = xout + (size_t)g0 * HH + cc0;
    float* o1 = o0 + HH;
    float4 va, vb;
    va.x = di0 * fmaxf(y0[0], 0.f); va.y = di0 * fmaxf(y0[1], 0.f);
    va.z = di0 * fmaxf(y0[2], 0.f); va.w = di0 * fmaxf(y0[3], 0.f);
    vb.x = di0 * fmaxf(y0[4], 0.f); vb.y = di0 * fmaxf(y0[5], 0.f);
    vb.z = di0 * fmaxf(y0[6], 0.f); vb.w = di0 * fmaxf(y0[7], 0.f);
    *(float4*)o0 = va; *(float4*)(o0 + 4) = vb;
    va.x = di1 * fmaxf(y1[0], 0.f); va.y = di1 * fmaxf(y1[1], 0.f);
    va.z = di1 * fmaxf(y1[2], 0.f); va.w = di1 * fmaxf(y1[3], 0.f);
    vb.x = di1 * fmaxf(y1[4], 0.f); vb.y = di1 * fmaxf(y1[5], 0.f);
    vb.z = di1 * fmaxf(y1[6], 0.f); vb.w = di1 * fmaxf(y1[7], 0.f);
    *(float4*)o1 = va; *(float4*)(o1 + 4) = vb;
}

// K4: layer 2 + FC head + state update + output write
__global__ __launch_bounds__(256, 2) void k_last(const float* __restrict__ xin,
                                                 const float* __restrict__ dinv,
                                                 const int* __restrict__ nbr,
                                                 const int* __restrict__ cnt4,
                                                 const float* __restrict__ W2,
                                                 const float* __restrict__ b2,
                                                 const float* __restrict__ Wfc,
                                                 const float* __restrict__ bfc,
                                                 const float* __restrict__ padding,
                                                 float* __restrict__ states,
                                                 float* __restrict__ outt) {
    __shared__ float uS[32][HH + 4];
    __shared__ float y3[32][HH + 4];
    __shared__ float wfcS[HH * 6];
    int b = blockIdx.x & 7;
    int tile = blockIdx.x >> 3;
    for (int q = threadIdx.x; q < HH * 6; q += 256) wfcS[q] = Wfc[q];
    gather_into_lds(xin, dinv, nbr, cnt4, b, tile, uS);
    __syncthreads();
    int cb = threadIdx.x & 15;
    int n0 = (threadIdx.x >> 4) * 2;
    int cc0 = cb * 8;
    float y0[8], y1[8];
    gemm_tile(uS, W2, b2, y0, y1, n0, cc0);
#pragma unroll
    for (int r = 0; r < 8; ++r) {
        y3[n0][cc0 + r]     = fmaxf(y0[r], 0.f);
        y3[n0 + 1][cc0 + r] = fmaxf(y1[r], 0.f);
    }
    __syncthreads();
    if (threadIdx.x < 192) {
        int n = threadIdx.x / 6;
        int c = threadIdx.x - n * 6;
        float r = bfc[c];
        for (int k = 0; k < HH; k += 4) {
            float yv[4];
            *(float4*)yv = *(const float4*)&y3[n][k];
            r = fmaf(yv[0], wfcS[(k + 0) * 6 + c], r);
            r = fmaf(yv[1], wfcS[(k + 1) * 6 + c], r);
            r = fmaf(yv[2], wfcS[(k + 2) * 6 + c], r);
            r = fmaf(yv[3], wfcS[(k + 3) * 6 + c], r);
        }
        int i = tile * 32 + n;
        int gi = b * NN + i;
        float pv = padding[b * NN + i];   // all-ones in this setup
        float s = states[(size_t)gi * 6 + c] + r * pv;
        states[(size_t)gi * 6 + c] = s;
        if (c < 3) outt[(size_t)b * OUT_BSTRIDE + i * 3 + c] = s;
    }
}

// ---------------------------------------------------------------------------
extern "C" void kernel_launch(void* const* d_in, const int* in_sizes, int n_in,
                              void* d_out, int out_size, void* d_ws, size_t ws_size,
                              hipStream_t stream) {
    (void)in_sizes; (void)n_in; (void)out_size; (void)ws_size;
    const float* points  = (const float*)d_in[0];
    const float* padding = (const float*)d_in[5];
    const float* W0  = (const float*)d_in[6];
    const float* b0  = (const float*)d_in[7];
    const float* W1  = (const float*)d_in[8];
    const float* b1  = (const float*)d_in[9];
    const float* W2  = (const float*)d_in[10];
    const float* b2  = (const float*)d_in[11];
    const float* Wfc = (const float*)d_in[12];
    const float* bfc = (const float*)d_in[13];
    float* out = (float*)d_out;

    // workspace carve-up (~24.2 MB total)
    float* ws     = (float*)d_ws;
    float* states = ws;                       // BB*NN*6
    float* xs0    = states + BB * NN * 6;     // BB*NN*6
    float* xs1    = xs0 + BB * NN * 6;        // BB*NN*HH
    float* xs2    = xs1 + BB * NN * HH;       // BB*NN*HH
    float* dinvp  = xs2 + BB * NN * HH;       // BB*NN
    int*   nbr    = (int*)(dinvp + BB * NN);  // BB*NN*MAXNBR
    int*   cnt4   = nbr + BB * NN * MAXNBR;   // BB*NN*4

    k_init<<<(BB * NN) / 256, 256, 0, stream>>>(points, states, out);
    for (int t = 0; t < PREDL; ++t) {
        k_adj<<<256, 256, 0, stream>>>(states, xs0, dinvp, nbr, cnt4);
        k_l0<<<256, 256, 0, stream>>>(xs0, dinvp, nbr, cnt4, W0, b0, xs1);
        k_mid<<<512, 256, 0, stream>>>(xs1, dinvp, nbr, cnt4, W1, b1, xs2);
        k_last<<<512, 256, 0, stream>>>(xs2, dinvp, nbr, cnt4, W2, b2, Wfc, bfc,
                                        padding, states,
                                        out + (size_t)(t + 1) * TSTRIDE);
    }
}

// Round 2
// 1021.310 us; speedup vs baseline: 1.1970x; 1.1970x over previous
//
#include <hip/hip_runtime.h>
#include <math.h>

// Problem constants (fixed by setup_inputs)
#define BB 8
#define NN 2048
#define HH 128
#define NSEG 8             // j-segments per node (256 j's each)
#define SEGJ 256
#define SEGCAP 12          // capacity per segment (Poisson mean ~1.1/seg)
#define MAXNBR (NSEG*SEGCAP)  // 96 per node
#define PREDL 10
#define TSTRIDE (NN*3)
#define OUT_BSTRIDE ((PREDL+1)*NN*3)

// ---------------------------------------------------------------------------
// K0: states0 = [points, 0]; write t=0 output slice
// ---------------------------------------------------------------------------
__global__ __launch_bounds__(256) void k_init(const float* __restrict__ points,
                                              float* __restrict__ states,
                                              float* __restrict__ out) {
    int idx = blockIdx.x * 256 + threadIdx.x;
    if (idx >= BB * NN) return;
    int b = idx >> 11;
    int n = idx & 2047;
    float px = points[idx * 3 + 0];
    float py = points[idx * 3 + 1];
    float pz = points[idx * 3 + 2];
    float* s = states + (size_t)idx * 6;
    s[0] = px; s[1] = py; s[2] = pz; s[3] = 0.f; s[4] = 0.f; s[5] = 0.f;
    float* o = out + (size_t)b * OUT_BSTRIDE + n * 3;
    o[0] = px; o[1] = py; o[2] = pz;
}

// ---------------------------------------------------------------------------
// K1: radius-graph (d2 < R^2, j != i), degree, dinv = 1/sqrt(deg+1),
//     xs0 = dinv * states.
// d2 in numpy's exact rounding order (no fma) -> step-1 adjacency bit-exact.
// grid: 512 blocks (b = blk&7 -> XCD locality, 32 nodes/block), 256 thr.
// Lane map: node = tid&31, seg = tid>>5. A wave = 2 segs x 32 nodes, so an
// inner-loop pos[j] read is <=2 distinct LDS addresses (2-way aliasing is
// free per m136; same-seg lanes broadcast). This kills the R1 4-way bank
// conflict (1.26e7 SQ_LDS_BANK_CONFLICT) and doubles blocks/CU.
// ---------------------------------------------------------------------------
__global__ __launch_bounds__(256, 2) void k_adj(const float* __restrict__ states,
                                                float* __restrict__ xs0,
                                                float* __restrict__ dinv,
                                                int* __restrict__ nbr,
                                                unsigned char* __restrict__ cnt8) {
    const float R2c = 0.01f;
    int b = blockIdx.x & 7;
    int tile = blockIdx.x >> 3;
    __shared__ float4 pos[NN];      // 32 KiB
    __shared__ int degs[NSEG * 32];
    const float* sb = states + (size_t)b * NN * 6;
    for (int j = threadIdx.x; j < NN; j += 256) {
        const float* r = sb + j * 6;
        pos[j] = make_float4(r[0], r[1], r[2], 0.f);
    }
    __syncthreads();
    int node = threadIdx.x & 31;
    int seg  = threadIdx.x >> 5;     // 0..7
    int i = tile * 32 + node;
    int gi = b * NN + i;
    float4 pi = pos[i];
    int cnt = 0;
    int base = gi * MAXNBR + seg * SEGCAP;
    int j0 = seg * SEGJ;
#pragma unroll 4
    for (int j = j0; j < j0 + SEGJ; ++j) {
        float4 pj = pos[j];
        float dx = pi.x - pj.x;
        float dy = pi.y - pj.y;
        float dz = pi.z - pj.z;
        // exact np order: (dx*dx + dy*dy) + dz*dz, each op rounded, no fma
        float d2 = __fadd_rn(__fadd_rn(__fmul_rn(dx, dx), __fmul_rn(dy, dy)),
                             __fmul_rn(dz, dz));
        if (d2 < R2c && j != i) {
            if (cnt < SEGCAP) nbr[base + cnt] = j;
            cnt++;
        }
    }
    if (cnt > SEGCAP) cnt = SEGCAP;
    cnt8[gi * NSEG + seg] = (unsigned char)cnt;
    degs[seg * 32 + node] = cnt;
    __syncthreads();
    if (threadIdx.x < 32) {
        int n = threadIdx.x;
        int rs = 1;
#pragma unroll
        for (int s = 0; s < NSEG; ++s) rs += degs[s * 32 + n];
        float di = (float)(1.0 / sqrt((double)rs));  // correctly-rounded rsqrt
        int g = b * NN + tile * 32 + n;
        dinv[g] = di;
        const float* srow = sb + (tile * 32 + n) * 6;
        float* xr = xs0 + (size_t)g * 6;
#pragma unroll
        for (int c = 0; c < 6; ++c) xr[c] = di * srow[c];
    }
}

// ---------------------------------------------------------------------------
// K2: layer 0 (6 -> 128): u_i = dinv_i*(sum_nbr xs0_j + xs0_i);
//     xs1 = dinv_i * relu(u @ W0 + b0)
// grid: 256 blocks (64 nodes each), 256 thr (4 thr/node x 32 ch)
// ---------------------------------------------------------------------------
__global__ __launch_bounds__(256) void k_l0(const float* __restrict__ xs0,
                                            const float* __restrict__ dinv,
                                            const int* __restrict__ nbr,
                                            const unsigned char* __restrict__ cnt8,
                                            const float* __restrict__ W0,
                                            const float* __restrict__ b0,
                                            float* __restrict__ xs1) {
    int b = blockIdx.x & 7;
    int tile = blockIdx.x >> 3;
    int node = threadIdx.x >> 2;
    int part = threadIdx.x & 3;
    int i = tile * 64 + node;
    int gi = b * NN + i;
    float g[6];
    {
        const float* sr = xs0 + (size_t)gi * 6;
#pragma unroll
        for (int c = 0; c < 6; ++c) g[c] = sr[c];
    }
    const int* nb = nbr + gi * MAXNBR;
    const unsigned char* c8 = cnt8 + gi * NSEG;
#pragma unroll
    for (int s = 0; s < NSEG; ++s) {
        int c = c8[s];
        for (int k = 0; k < c; ++k) {
            int j = nb[s * SEGCAP + k];
            const float* xr = xs0 + (size_t)(b * NN + j) * 6;
#pragma unroll
            for (int q = 0; q < 6; ++q) g[q] += xr[q];
        }
    }
    float di = dinv[gi];
#pragma unroll
    for (int c = 0; c < 6; ++c) g[c] *= di;
    int c0 = part * 32;
    float y[32];
#pragma unroll
    for (int r = 0; r < 8; ++r) {
        float4 bv = *(const float4*)(b0 + c0 + r * 4);
        y[r * 4 + 0] = bv.x; y[r * 4 + 1] = bv.y; y[r * 4 + 2] = bv.z; y[r * 4 + 3] = bv.w;
    }
#pragma unroll
    for (int k = 0; k < 6; ++k) {
        float u = g[k];
        const float* wr = W0 + k * HH + c0;
#pragma unroll
        for (int r = 0; r < 8; ++r) {
            float4 w = *(const float4*)(wr + r * 4);
            y[r * 4 + 0] = fmaf(u, w.x, y[r * 4 + 0]);
            y[r * 4 + 1] = fmaf(u, w.y, y[r * 4 + 1]);
            y[r * 4 + 2] = fmaf(u, w.z, y[r * 4 + 2]);
            y[r * 4 + 3] = fmaf(u, w.w, y[r * 4 + 3]);
        }
    }
    float* xo = xs1 + (size_t)gi * HH + c0;
#pragma unroll
    for (int r = 0; r < 8; ++r) {
        float4 v;
        v.x = di * fmaxf(y[r * 4 + 0], 0.f);
        v.y = di * fmaxf(y[r * 4 + 1], 0.f);
        v.z = di * fmaxf(y[r * 4 + 2], 0.f);
        v.w = di * fmaxf(y[r * 4 + 3], 0.f);
        *(float4*)(xo + r * 4) = v;
    }
}

// ---------------------------------------------------------------------------
// Shared pieces for the 128->128 layers (32 nodes/block, 512 blocks).
// ---------------------------------------------------------------------------
__device__ __forceinline__ void gather_into_lds(const float* __restrict__ xin,
                                                const float* __restrict__ dinv,
                                                const int* __restrict__ nbr,
                                                const unsigned char* __restrict__ cnt8,
                                                int b, int tile,
                                                float (*uS)[HH + 4]) {
    const int node = threadIdx.x >> 3;   // 0..31
    const int part = threadIdx.x & 7;    // 16 ch each
    const int i = tile * 32 + node;
    const int gi = b * NN + i;
    const int c0 = part * 16;
    float acc[16];
    const float* xs = xin + (size_t)gi * HH + c0;
#pragma unroll
    for (int r = 0; r < 4; ++r) *(float4*)&acc[r * 4] = *(const float4*)(xs + r * 4);
    const int* nb = nbr + gi * MAXNBR;
    const unsigned char* c8 = cnt8 + gi * NSEG;
#pragma unroll
    for (int s = 0; s < NSEG; ++s) {
        const int c = c8[s];
        for (int k = 0; k < c; ++k) {
            const int j = nb[s * SEGCAP + k];
            const float* xr = xin + (size_t)(b * NN + j) * HH + c0;
#pragma unroll
            for (int r = 0; r < 4; ++r) {
                float v[4];
                *(float4*)v = *(const float4*)(xr + r * 4);
                acc[r * 4 + 0] += v[0]; acc[r * 4 + 1] += v[1];
                acc[r * 4 + 2] += v[2]; acc[r * 4 + 3] += v[3];
            }
        }
    }
    const float di = dinv[gi];
#pragma unroll
    for (int r = 0; r < 4; ++r) {
        float4 o;
        o.x = acc[r * 4 + 0] * di; o.y = acc[r * 4 + 1] * di;
        o.z = acc[r * 4 + 2] * di; o.w = acc[r * 4 + 3] * di;
        *(float4*)&uS[node][c0 + r * 4] = o;
    }
}

__device__ __forceinline__ void gemm_tile(const float (*uS)[HH + 4],
                                          const float* __restrict__ W,
                                          const float* __restrict__ bias,
                                          float y0[8], float y1[8],
                                          int n0, int cc0) {
    float4 bv0 = *(const float4*)(bias + cc0);
    float4 bv1 = *(const float4*)(bias + cc0 + 4);
    y0[0] = bv0.x; y0[1] = bv0.y; y0[2] = bv0.z; y0[3] = bv0.w;
    y0[4] = bv1.x; y0[5] = bv1.y; y0[6] = bv1.z; y0[7] = bv1.w;
#pragma unroll
    for (int r = 0; r < 8; ++r) y1[r] = y0[r];
#pragma unroll 2
    for (int k = 0; k < HH; k += 4) {
        float ua[4], ub[4];
        *(float4*)ua = *(const float4*)&uS[n0][k];
        *(float4*)ub = *(const float4*)&uS[n0 + 1][k];
        const float* wrow = W + k * HH + cc0;
#pragma unroll
        for (int q = 0; q < 4; ++q) {
            float4 wa = *(const float4*)(wrow + q * HH);
            float4 wb = *(const float4*)(wrow + q * HH + 4);
            float u0 = ua[q], u1 = ub[q];
            y0[0] = fmaf(u0, wa.x, y0[0]); y0[1] = fmaf(u0, wa.y, y0[1]);
            y0[2] = fmaf(u0, wa.z, y0[2]); y0[3] = fmaf(u0, wa.w, y0[3]);
            y0[4] = fmaf(u0, wb.x, y0[4]); y0[5] = fmaf(u0, wb.y, y0[5]);
            y0[6] = fmaf(u0, wb.z, y0[6]); y0[7] = fmaf(u0, wb.w, y0[7]);
            y1[0] = fmaf(u1, wa.x, y1[0]); y1[1] = fmaf(u1, wa.y, y1[1]);
            y1[2] = fmaf(u1, wa.z, y1[2]); y1[3] = fmaf(u1, wa.w, y1[3]);
            y1[4] = fmaf(u1, wb.x, y1[4]); y1[5] = fmaf(u1, wb.y, y1[5]);
            y1[6] = fmaf(u1, wb.z, y1[6]); y1[7] = fmaf(u1, wb.w, y1[7]);
        }
    }
}

// K3: middle layer (layer 1): xs_out = dinv * relu(u @ W + b)
__global__ __launch_bounds__(256, 4) void k_mid(const float* __restrict__ xin,
                                                const float* __restrict__ dinv,
                                                const int* __restrict__ nbr,
                                                const unsigned char* __restrict__ cnt8,
                                                const float* __restrict__ W,
                                                const float* __restrict__ bias,
                                                float* __restrict__ xout) {
    __shared__ float uS[32][HH + 4];
    int b = blockIdx.x & 7;
    int tile = blockIdx.x >> 3;
    gather_into_lds(xin, dinv, nbr, cnt8, b, tile, uS);
    __syncthreads();
    int cb = threadIdx.x & 15;
    int n0 = (threadIdx.x >> 4) * 2;
    int cc0 = cb * 8;
    float y0[8], y1[8];
    gemm_tile(uS, W, bias, y0, y1, n0, cc0);
    int g0 = b * NN + tile * 32 + n0;
    float di0 = dinv[g0], di1 = dinv[g0 + 1];
    float* o0 = xout + (size_t)g0 * HH + cc0;
    float* o1 = o0 + HH;
    float4 va, vb;
    va.x = di0 * fmaxf(y0[0], 0.f); va.y = di0 * fmaxf(y0[1], 0.f);
    va.z = di0 * fmaxf(y0[2], 0.f); va.w = di0 * fmaxf(y0[3], 0.f);
    vb.x = di0 * fmaxf(y0[4], 0.f); vb.y = di0 * fmaxf(y0[5], 0.f);
    vb.z = di0 * fmaxf(y0[6], 0.f); vb.w = di0 * fmaxf(y0[7], 0.f);
    *(float4*)o0 = va; *(float4*)(o0 + 4) = vb;
    va.x = di1 * fmaxf(y1[0], 0.f); va.y = di1 * fmaxf(y1[1], 0.f);
    va.z = di1 * fmaxf(y1[2], 0.f); va.w = di1 * fmaxf(y1[3], 0.f);
    vb.x = di1 * fmaxf(y1[4], 0.f); vb.y = di1 * fmaxf(y1[5], 0.f);
    vb.z = di1 * fmaxf(y1[6], 0.f); vb.w = di1 * fmaxf(y1[7], 0.f);
    *(float4*)o1 = va; *(float4*)(o1 + 4) = vb;
}

// K4: layer 2 + FC head + state update + output write
__global__ __launch_bounds__(256, 4) void k_last(const float* __restrict__ xin,
                                                 const float* __restrict__ dinv,
                                                 const int* __restrict__ nbr,
                                                 const unsigned char* __restrict__ cnt8,
                                                 const float* __restrict__ W2,
                                                 const float* __restrict__ b2,
                                                 const float* __restrict__ Wfc,
                                                 const float* __restrict__ bfc,
                                                 const float* __restrict__ padding,
                                                 float* __restrict__ states,
                                                 float* __restrict__ outt) {
    __shared__ float uS[32][HH + 4];
    __shared__ float y3[32][HH + 4];
    __shared__ float wfcS[HH * 6];
    int b = blockIdx.x & 7;
    int tile = blockIdx.x >> 3;
    for (int q = threadIdx.x; q < HH * 6; q += 256) wfcS[q] = Wfc[q];
    gather_into_lds(xin, dinv, nbr, cnt8, b, tile, uS);
    __syncthreads();
    int cb = threadIdx.x & 15;
    int n0 = (threadIdx.x >> 4) * 2;
    int cc0 = cb * 8;
    float y0[8], y1[8];
    gemm_tile(uS, W2, b2, y0, y1, n0, cc0);
#pragma unroll
    for (int r = 0; r < 8; ++r) {
        y3[n0][cc0 + r]     = fmaxf(y0[r], 0.f);
        y3[n0 + 1][cc0 + r] = fmaxf(y1[r], 0.f);
    }
    __syncthreads();
    if (threadIdx.x < 192) {
        int n = threadIdx.x / 6;
        int c = threadIdx.x - n * 6;
        float r = bfc[c];
        for (int k = 0; k < HH; k += 4) {
            float yv[4];
            *(float4*)yv = *(const float4*)&y3[n][k];
            r = fmaf(yv[0], wfcS[(k + 0) * 6 + c], r);
            r = fmaf(yv[1], wfcS[(k + 1) * 6 + c], r);
            r = fmaf(yv[2], wfcS[(k + 2) * 6 + c], r);
            r = fmaf(yv[3], wfcS[(k + 3) * 6 + c], r);
        }
        int i = tile * 32 + n;
        int gi = b * NN + i;
        float pv = padding[b * NN + i];   // all-ones in this setup
        float s = states[(size_t)gi * 6 + c] + r * pv;
        states[(size_t)gi * 6 + c] = s;
        if (c < 3) outt[(size_t)b * OUT_BSTRIDE + i * 3 + c] = s;
    }
}

// ---------------------------------------------------------------------------
extern "C" void kernel_launch(void* const* d_in, const int* in_sizes, int n_in,
                              void* d_out, int out_size, void* d_ws, size_t ws_size,
                              hipStream_t stream) {
    (void)in_sizes; (void)n_in; (void)out_size; (void)ws_size;
    const float* points  = (const float*)d_in[0];
    const float* padding = (const float*)d_in[5];
    const float* W0  = (const float*)d_in[6];
    const float* b0  = (const float*)d_in[7];
    const float* W1  = (const float*)d_in[8];
    const float* b1  = (const float*)d_in[9];
    const float* W2  = (const float*)d_in[10];
    const float* b2  = (const float*)d_in[11];
    const float* Wfc = (const float*)d_in[12];
    const float* bfc = (const float*)d_in[13];
    float* out = (float*)d_out;

    // workspace carve-up (~24.05 MB total, <= R1's 24.18 MB high-water mark)
    float* ws     = (float*)d_ws;
    float* states = ws;                       // BB*NN*6
    float* xs0    = states + BB * NN * 6;     // BB*NN*6
    float* xs1    = xs0 + BB * NN * 6;        // BB*NN*HH
    float* xs2    = xs1 + BB * NN * HH;       // BB*NN*HH
    float* dinvp  = xs2 + BB * NN * HH;       // BB*NN
    int*   nbr    = (int*)(dinvp + BB * NN);  // BB*NN*MAXNBR
    unsigned char* cnt8 = (unsigned char*)(nbr + BB * NN * MAXNBR); // BB*NN*NSEG

    k_init<<<(BB * NN) / 256, 256, 0, stream>>>(points, states, out);
    for (int t = 0; t < PREDL; ++t) {
        k_adj<<<512, 256, 0, stream>>>(states, xs0, dinvp, nbr, cnt8);
        k_l0<<<256, 256, 0, stream>>>(xs0, dinvp, nbr, cnt8, W0, b0, xs1);
        k_mid<<<512, 256, 0, stream>>>(xs1, dinvp, nbr, cnt8, W1, b1, xs2);
        k_last<<<512, 256, 0, stream>>>(xs2, dinvp, nbr, cnt8, W2, b2, Wfc, bfc,
                                        padding, states,
                                        out + (size_t)(t + 1) * TSTRIDE);
    }
}

// Round 3
// 835.568 us; speedup vs baseline: 1.4631x; 1.2223x over previous
//
#include <hip/hip_runtime.h>
#include <math.h>

// Problem constants (fixed by setup_inputs)
#define BB 8
#define NN 2048
#define HH 128
#define NSEG 8             // j-segments per node (256 j's each)
#define SEGJ 256
#define SEGCAP 12          // capacity per segment (Poisson mean ~1.1/seg)
#define MAXNBR (NSEG*SEGCAP)  // 96 per node
#define PREDL 10
#define TSTRIDE (NN*3)
#define OUT_BSTRIDE ((PREDL+1)*NN*3)

// ---------------------------------------------------------------------------
// K0: states0 = [points, 0]; write t=0 output slice
// ---------------------------------------------------------------------------
__global__ __launch_bounds__(256) void k_init(const float* __restrict__ points,
                                              float* __restrict__ states,
                                              float* __restrict__ out) {
    int idx = blockIdx.x * 256 + threadIdx.x;
    if (idx >= BB * NN) return;
    int b = idx >> 11;
    int n = idx & 2047;
    float px = points[idx * 3 + 0];
    float py = points[idx * 3 + 1];
    float pz = points[idx * 3 + 2];
    float* s = states + (size_t)idx * 6;
    s[0] = px; s[1] = py; s[2] = pz; s[3] = 0.f; s[4] = 0.f; s[5] = 0.f;
    float* o = out + (size_t)b * OUT_BSTRIDE + n * 3;
    o[0] = px; o[1] = py; o[2] = pz;
}

// ---------------------------------------------------------------------------
// K1: radius-graph + COMPACTED flat neighbor list per node (ascending j,
// same summation order as before -> bit-identical downstream sums).
// d2 in numpy's exact rounding order (no fma) -> step-1 adjacency bit-exact.
// Lane map: node = tid&31, seg = tid>>5 (wave = 2 segs x 32 nodes ->
// pos[j] reads are <=2 distinct LDS addrs = conflict-free per m136).
// Segment hits staged in LDS (ushort), then prefix-compacted to global.
// ---------------------------------------------------------------------------
__global__ __launch_bounds__(256, 2) void k_adj(const float* __restrict__ states,
                                                float* __restrict__ xs0,
                                                float* __restrict__ dinv,
                                                int* __restrict__ nbr,
                                                int* __restrict__ cntN) {
    const float R2c = 0.01f;
    int b = blockIdx.x & 7;
    int tile = blockIdx.x >> 3;
    __shared__ float4 pos[NN];                  // 32 KiB
    __shared__ int degs[256];                   // 1 KiB
    __shared__ unsigned short jb[256][SEGCAP];  // 6 KiB
    const float* sb = states + (size_t)b * NN * 6;
    for (int j = threadIdx.x; j < NN; j += 256) {
        const float* r = sb + j * 6;
        pos[j] = make_float4(r[0], r[1], r[2], 0.f);
    }
    __syncthreads();
    int node = threadIdx.x & 31;
    int seg  = threadIdx.x >> 5;     // 0..7
    int i = tile * 32 + node;
    int gi = b * NN + i;
    float4 pi = pos[i];
    int cnt = 0;
    int j0 = seg * SEGJ;
#pragma unroll 4
    for (int j = j0; j < j0 + SEGJ; ++j) {
        float4 pj = pos[j];
        float dx = pi.x - pj.x;
        float dy = pi.y - pj.y;
        float dz = pi.z - pj.z;
        // exact np order: (dx*dx + dy*dy) + dz*dz, each op rounded, no fma
        float d2 = __fadd_rn(__fadd_rn(__fmul_rn(dx, dx), __fmul_rn(dy, dy)),
                             __fmul_rn(dz, dz));
        if (d2 < R2c && j != i) {
            if (cnt < SEGCAP) jb[threadIdx.x][cnt] = (unsigned short)j;
            cnt++;
        }
    }
    if (cnt > SEGCAP) cnt = SEGCAP;
    degs[threadIdx.x] = cnt;
    __syncthreads();
    // prefix over lower segments of this node -> compact, j-ascending
    int off = 0;
    for (int s = 0; s < seg; ++s) off += degs[s * 32 + node];
    int base = gi * MAXNBR + off;
    for (int k = 0; k < cnt; ++k) nbr[base + k] = (int)jb[threadIdx.x][k];
    if (seg == NSEG - 1) {
        int tot = off + cnt;
        cntN[gi] = tot;
        float di = (float)(1.0 / sqrt((double)(1 + tot)));  // exact rsqrt
        dinv[gi] = di;
        const float* srow = sb + (size_t)i * 6;
        float* xr = xs0 + (size_t)gi * 6;
#pragma unroll
        for (int c = 0; c < 6; ++c) xr[c] = di * srow[c];
    }
}

// ---------------------------------------------------------------------------
// K2: layer 0 (6 -> 128). 512 blocks, 32 nodes x 8 ch-parts (16 ch each).
// ---------------------------------------------------------------------------
__global__ __launch_bounds__(256, 2) void k_l0(const float* __restrict__ xs0,
                                               const float* __restrict__ dinv,
                                               const int* __restrict__ nbr,
                                               const int* __restrict__ cntN,
                                               const float* __restrict__ W0,
                                               const float* __restrict__ b0,
                                               float* __restrict__ xs1) {
    int b = blockIdx.x & 7;
    int tile = blockIdx.x >> 3;
    int node = threadIdx.x >> 3;
    int part = threadIdx.x & 7;
    int i = tile * 32 + node;
    int gi = b * NN + i;
    float g[6];
    {
        const float* sr = xs0 + (size_t)gi * 6;
        float2 a0 = *(const float2*)sr;
        float2 a1 = *(const float2*)(sr + 2);
        float2 a2 = *(const float2*)(sr + 4);
        g[0] = a0.x; g[1] = a0.y; g[2] = a1.x; g[3] = a1.y; g[4] = a2.x; g[5] = a2.y;
    }
    int cnt = cntN[gi];
    const int* nb = nbr + gi * MAXNBR;
    for (int k = 0; k < cnt; ++k) {
        int j = nb[k];
        const float* xr = xs0 + (size_t)(b * NN + j) * 6;
        float2 v0 = *(const float2*)xr;
        float2 v1 = *(const float2*)(xr + 2);
        float2 v2 = *(const float2*)(xr + 4);
        g[0] += v0.x; g[1] += v0.y; g[2] += v1.x;
        g[3] += v1.y; g[4] += v2.x; g[5] += v2.y;
    }
    float di = dinv[gi];
#pragma unroll
    for (int c = 0; c < 6; ++c) g[c] *= di;
    int c0 = part * 16;
    float y[16];
#pragma unroll
    for (int r = 0; r < 4; ++r) {
        float4 bv = *(const float4*)(b0 + c0 + r * 4);
        y[r * 4 + 0] = bv.x; y[r * 4 + 1] = bv.y; y[r * 4 + 2] = bv.z; y[r * 4 + 3] = bv.w;
    }
#pragma unroll
    for (int k = 0; k < 6; ++k) {
        float u = g[k];
        const float* wr = W0 + k * HH + c0;
#pragma unroll
        for (int r = 0; r < 4; ++r) {
            float4 w = *(const float4*)(wr + r * 4);
            y[r * 4 + 0] = fmaf(u, w.x, y[r * 4 + 0]);
            y[r * 4 + 1] = fmaf(u, w.y, y[r * 4 + 1]);
            y[r * 4 + 2] = fmaf(u, w.z, y[r * 4 + 2]);
            y[r * 4 + 3] = fmaf(u, w.w, y[r * 4 + 3]);
        }
    }
    float* xo = xs1 + (size_t)gi * HH + c0;
#pragma unroll
    for (int r = 0; r < 4; ++r) {
        float4 v;
        v.x = di * fmaxf(y[r * 4 + 0], 0.f);
        v.y = di * fmaxf(y[r * 4 + 1], 0.f);
        v.z = di * fmaxf(y[r * 4 + 2], 0.f);
        v.w = di * fmaxf(y[r * 4 + 3], 0.f);
        *(float4*)(xo + r * 4) = v;
    }
}

// ---------------------------------------------------------------------------
// 128->128 layers: gather u-tile to LDS, then GEMM with W staged through
// double-buffered 32-row LDS panels (global W read exactly once per block).
// LDS: uS 16.9 KB + wS 32 KB = 48.9 KB -> 3 blocks/CU.
// ---------------------------------------------------------------------------
__device__ __forceinline__ void gather_into_lds(const float* __restrict__ xin,
                                                const float* __restrict__ dinv,
                                                const int* __restrict__ nbr,
                                                const int* __restrict__ cntN,
                                                int b, int tile,
                                                float (*uS)[HH + 4]) {
    const int node = threadIdx.x >> 3;   // 0..31
    const int part = threadIdx.x & 7;    // 16 ch each
    const int i = tile * 32 + node;
    const int gi = b * NN + i;
    const int c0 = part * 16;
    float acc[16];
    const float* xs = xin + (size_t)gi * HH + c0;
#pragma unroll
    for (int r = 0; r < 4; ++r) *(float4*)&acc[r * 4] = *(const float4*)(xs + r * 4);
    const int cnt = cntN[gi];
    const int* nb = nbr + gi * MAXNBR;
    for (int k = 0; k < cnt; ++k) {
        const int j = nb[k];
        const float* xr = xin + (size_t)(b * NN + j) * HH + c0;
#pragma unroll
        for (int r = 0; r < 4; ++r) {
            float v[4];
            *(float4*)v = *(const float4*)(xr + r * 4);
            acc[r * 4 + 0] += v[0]; acc[r * 4 + 1] += v[1];
            acc[r * 4 + 2] += v[2]; acc[r * 4 + 3] += v[3];
        }
    }
    const float di = dinv[gi];
#pragma unroll
    for (int r = 0; r < 4; ++r) {
        float4 o;
        o.x = acc[r * 4 + 0] * di; o.y = acc[r * 4 + 1] * di;
        o.z = acc[r * 4 + 2] * di; o.w = acc[r * 4 + 3] * di;
        *(float4*)&uS[node][c0 + r * 4] = o;
    }
}

// GEMM over one 32-row W panel held in LDS. Thread owns 2 nodes x 8 ch.
__device__ __forceinline__ void gemm_panel(const float (*uS)[HH + 4],
                                           const float* __restrict__ wbuf,
                                           int p, int n0, int cc0,
                                           float y0[8], float y1[8]) {
#pragma unroll 2
    for (int r = 0; r < 32; r += 4) {
        float ua[4], ub[4];
        *(float4*)ua = *(const float4*)(&uS[n0][p * 32 + r]);
        *(float4*)ub = *(const float4*)(&uS[n0 + 1][p * 32 + r]);
        const float* wrow = wbuf + r * HH + cc0;
#pragma unroll
        for (int q = 0; q < 4; ++q) {
            float4 wa = *(const float4*)(wrow + q * HH);
            float4 wb = *(const float4*)(wrow + q * HH + 4);
            float u0 = ua[q], u1 = ub[q];
            y0[0] = fmaf(u0, wa.x, y0[0]); y0[1] = fmaf(u0, wa.y, y0[1]);
            y0[2] = fmaf(u0, wa.z, y0[2]); y0[3] = fmaf(u0, wa.w, y0[3]);
            y0[4] = fmaf(u0, wb.x, y0[4]); y0[5] = fmaf(u0, wb.y, y0[5]);
            y0[6] = fmaf(u0, wb.z, y0[6]); y0[7] = fmaf(u0, wb.w, y0[7]);
            y1[0] = fmaf(u1, wa.x, y1[0]); y1[1] = fmaf(u1, wa.y, y1[1]);
            y1[2] = fmaf(u1, wa.z, y1[2]); y1[3] = fmaf(u1, wa.w, y1[3]);
            y1[4] = fmaf(u1, wb.x, y1[4]); y1[5] = fmaf(u1, wb.y, y1[5]);
            y1[6] = fmaf(u1, wb.z, y1[6]); y1[7] = fmaf(u1, wb.w, y1[7]);
        }
    }
}

// K3: middle layer (layer 1): xs_out = dinv * relu(u @ W + b)
__global__ __launch_bounds__(256, 3) void k_mid(const float* __restrict__ xin,
                                                const float* __restrict__ dinv,
                                                const int* __restrict__ nbr,
                                                const int* __restrict__ cntN,
                                                const float* __restrict__ W,
                                                const float* __restrict__ bias,
                                                float* __restrict__ xout) {
    __shared__ __align__(16) float uS[32][HH + 4];
    __shared__ __align__(16) float wS[2][32 * HH];
    int b = blockIdx.x & 7;
    int tile = blockIdx.x >> 3;
    int t = threadIdx.x;
    const float4* Wf4 = (const float4*)W;
    float4 wreg[4];
#pragma unroll
    for (int q = 0; q < 4; ++q) wreg[q] = Wf4[t + q * 256];   // panel 0
    gather_into_lds(xin, dinv, nbr, cntN, b, tile, uS);
    {
        float4* ws4 = (float4*)wS[0];
#pragma unroll
        for (int q = 0; q < 4; ++q) ws4[t + q * 256] = wreg[q];
    }
    __syncthreads();
    int cb = t & 15, ng = t >> 4;
    int n0 = ng * 2, cc0 = cb * 8;
    float y0[8], y1[8];
    {
        float4 bv0 = *(const float4*)(bias + cc0);
        float4 bv1 = *(const float4*)(bias + cc0 + 4);
        y0[0] = bv0.x; y0[1] = bv0.y; y0[2] = bv0.z; y0[3] = bv0.w;
        y0[4] = bv1.x; y0[5] = bv1.y; y0[6] = bv1.z; y0[7] = bv1.w;
#pragma unroll
        for (int r = 0; r < 8; ++r) y1[r] = y0[r];
    }
#pragma unroll
    for (int p = 0; p < 4; ++p) {
        if (p < 3) {
#pragma unroll
            for (int q = 0; q < 4; ++q) wreg[q] = Wf4[(p + 1) * 1024 + t + q * 256];
        }
        gemm_panel(uS, wS[p & 1], p, n0, cc0, y0, y1);
        if (p < 3) {
            float4* ws4 = (float4*)wS[1 - (p & 1)];
#pragma unroll
            for (int q = 0; q < 4; ++q) ws4[t + q * 256] = wreg[q];
            __syncthreads();
        }
    }
    int g0 = b * NN + tile * 32 + n0;
    float di0 = dinv[g0], di1 = dinv[g0 + 1];
    float* o0 = xout + (size_t)g0 * HH + cc0;
    float* o1 = o0 + HH;
    float4 va, vb;
    va.x = di0 * fmaxf(y0[0], 0.f); va.y = di0 * fmaxf(y0[1], 0.f);
    va.z = di0 * fmaxf(y0[2], 0.f); va.w = di0 * fmaxf(y0[3], 0.f);
    vb.x = di0 * fmaxf(y0[4], 0.f); vb.y = di0 * fmaxf(y0[5], 0.f);
    vb.z = di0 * fmaxf(y0[6], 0.f); vb.w = di0 * fmaxf(y0[7], 0.f);
    *(float4*)o0 = va; *(float4*)(o0 + 4) = vb;
    va.x = di1 * fmaxf(y1[0], 0.f); va.y = di1 * fmaxf(y1[1], 0.f);
    va.z = di1 * fmaxf(y1[2], 0.f); va.w = di1 * fmaxf(y1[3], 0.f);
    vb.x = di1 * fmaxf(y1[4], 0.f); vb.y = di1 * fmaxf(y1[5], 0.f);
    vb.z = di1 * fmaxf(y1[6], 0.f); vb.w = di1 * fmaxf(y1[7], 0.f);
    *(float4*)o1 = va; *(float4*)(o1 + 4) = vb;
}

// K4: layer 2 + FC head + state update + output write.
// After the last panel, wS[0] is reused as y3[32][128] and wS[1] as wfcS.
__global__ __launch_bounds__(256, 3) void k_last(const float* __restrict__ xin,
                                                 const float* __restrict__ dinv,
                                                 const int* __restrict__ nbr,
                                                 const int* __restrict__ cntN,
                                                 const float* __restrict__ W2,
                                                 const float* __restrict__ b2,
                                                 const float* __restrict__ Wfc,
                                                 const float* __restrict__ bfc,
                                                 const float* __restrict__ padding,
                                                 float* __restrict__ states,
                                                 float* __restrict__ outt) {
    __shared__ __align__(16) float uS[32][HH + 4];
    __shared__ __align__(16) float wS[2][32 * HH];
    int b = blockIdx.x & 7;
    int tile = blockIdx.x >> 3;
    int t = threadIdx.x;
    const float4* Wf4 = (const float4*)W2;
    float4 wreg[4];
#pragma unroll
    for (int q = 0; q < 4; ++q) wreg[q] = Wf4[t + q * 256];
    gather_into_lds(xin, dinv, nbr, cntN, b, tile, uS);
    {
        float4* ws4 = (float4*)wS[0];
#pragma unroll
        for (int q = 0; q < 4; ++q) ws4[t + q * 256] = wreg[q];
    }
    __syncthreads();
    int cb = t & 15, ng = t >> 4;
    int n0 = ng * 2, cc0 = cb * 8;
    float y0[8], y1[8];
    {
        float4 bv0 = *(const float4*)(b2 + cc0);
        float4 bv1 = *(const float4*)(b2 + cc0 + 4);
        y0[0] = bv0.x; y0[1] = bv0.y; y0[2] = bv0.z; y0[3] = bv0.w;
        y0[4] = bv1.x; y0[5] = bv1.y; y0[6] = bv1.z; y0[7] = bv1.w;
#pragma unroll
        for (int r = 0; r < 8; ++r) y1[r] = y0[r];
    }
#pragma unroll
    for (int p = 0; p < 4; ++p) {
        if (p < 3) {
#pragma unroll
            for (int q = 0; q < 4; ++q) wreg[q] = Wf4[(p + 1) * 1024 + t + q * 256];
        }
        gemm_panel(uS, wS[p & 1], p, n0, cc0, y0, y1);
        if (p < 3) {
            float4* ws4 = (float4*)wS[1 - (p & 1)];
#pragma unroll
            for (int q = 0; q < 4; ++q) ws4[t + q * 256] = wreg[q];
            __syncthreads();
        }
    }
    __syncthreads();   // all panel reads done; reuse wS
    float* y3  = wS[0];   // [32][HH]
    float* wfc = wS[1];   // HH*6 floats
#pragma unroll
    for (int q = 0; q < 3; ++q) wfc[t + q * 256] = Wfc[t + q * 256];
    {
        float4 v;
        v.x = fmaxf(y0[0], 0.f); v.y = fmaxf(y0[1], 0.f);
        v.z = fmaxf(y0[2], 0.f); v.w = fmaxf(y0[3], 0.f);
        *(float4*)&y3[n0 * HH + cc0] = v;
        v.x = fmaxf(y0[4], 0.f); v.y = fmaxf(y0[5], 0.f);
        v.z = fmaxf(y0[6], 0.f); v.w = fmaxf(y0[7], 0.f);
        *(float4*)&y3[n0 * HH + cc0 + 4] = v;
        v.x = fmaxf(y1[0], 0.f); v.y = fmaxf(y1[1], 0.f);
        v.z = fmaxf(y1[2], 0.f); v.w = fmaxf(y1[3], 0.f);
        *(float4*)&y3[(n0 + 1) * HH + cc0] = v;
        v.x = fmaxf(y1[4], 0.f); v.y = fmaxf(y1[5], 0.f);
        v.z = fmaxf(y1[6], 0.f); v.w = fmaxf(y1[7], 0.f);
        *(float4*)&y3[(n0 + 1) * HH + cc0 + 4] = v;
    }
    __syncthreads();
    if (t < 192) {
        int n = t / 6;
        int c = t - n * 6;
        float r = bfc[c];
        for (int k = 0; k < HH; k += 4) {
            float yv[4];
            *(float4*)yv = *(const float4*)&y3[n * HH + k];
            r = fmaf(yv[0], wfc[(k + 0) * 6 + c], r);
            r = fmaf(yv[1], wfc[(k + 1) * 6 + c], r);
            r = fmaf(yv[2], wfc[(k + 2) * 6 + c], r);
            r = fmaf(yv[3], wfc[(k + 3) * 6 + c], r);
        }
        int i = tile * 32 + n;
        int gi = b * NN + i;
        float pv = padding[b * NN + i];   // all-ones in this setup
        float s = states[(size_t)gi * 6 + c] + r * pv;
        states[(size_t)gi * 6 + c] = s;
        if (c < 3) outt[(size_t)b * OUT_BSTRIDE + i * 3 + c] = s;
    }
}

// ---------------------------------------------------------------------------
extern "C" void kernel_launch(void* const* d_in, const int* in_sizes, int n_in,
                              void* d_out, int out_size, void* d_ws, size_t ws_size,
                              hipStream_t stream) {
    (void)in_sizes; (void)n_in; (void)out_size; (void)ws_size;
    const float* points  = (const float*)d_in[0];
    const float* padding = (const float*)d_in[5];
    const float* W0  = (const float*)d_in[6];
    const float* b0  = (const float*)d_in[7];
    const float* W1  = (const float*)d_in[8];
    const float* b1  = (const float*)d_in[9];
    const float* W2  = (const float*)d_in[10];
    const float* b2  = (const float*)d_in[11];
    const float* Wfc = (const float*)d_in[12];
    const float* bfc = (const float*)d_in[13];
    float* out = (float*)d_out;

    // workspace carve-up (~24 MB)
    float* ws     = (float*)d_ws;
    float* states = ws;                       // BB*NN*6
    float* xs0    = states + BB * NN * 6;     // BB*NN*6
    float* xs1    = xs0 + BB * NN * 6;        // BB*NN*HH
    float* xs2    = xs1 + BB * NN * HH;       // BB*NN*HH
    float* dinvp  = xs2 + BB * NN * HH;       // BB*NN
    int*   nbr    = (int*)(dinvp + BB * NN);  // BB*NN*MAXNBR
    int*   cntN   = nbr + BB * NN * MAXNBR;   // BB*NN

    k_init<<<(BB * NN) / 256, 256, 0, stream>>>(points, states, out);
    for (int t = 0; t < PREDL; ++t) {
        k_adj<<<512, 256, 0, stream>>>(states, xs0, dinvp, nbr, cntN);
        k_l0<<<512, 256, 0, stream>>>(xs0, dinvp, nbr, cntN, W0, b0, xs1);
        k_mid<<<512, 256, 0, stream>>>(xs1, dinvp, nbr, cntN, W1, b1, xs2);
        k_last<<<512, 256, 0, stream>>>(xs2, dinvp, nbr, cntN, W2, b2, Wfc, bfc,
                                        padding, states,
                                        out + (size_t)(t + 1) * TSTRIDE);
    }
}